// Round 14
// baseline (215.586 us; speedup 1.0000x reference)
//
#include <hip/hip_runtime.h>
#include <hip/hip_bf16.h>

#define N_NODES 51200
#define N_EDGES 819200
#define N_GRAPHS 256

typedef __attribute__((ext_vector_type(8))) short short8;
typedef __attribute__((ext_vector_type(4))) float f32x4;

__device__ __forceinline__ ushort f2bf(float f) {
    uint u = __builtin_bit_cast(uint, f);
    u += 0x7FFFu + ((u >> 16) & 1u);     // round-to-nearest-even
    return (ushort)(u >> 16);
}
__device__ __forceinline__ float bf2f(ushort h) {
    uint u = ((uint)h) << 16;
    return __builtin_bit_cast(float, u);
}

// ---------------------------------------------------------------------------
// k_init: zero hg + cnt, pack conv weights, build bias_cat[176]
// ---------------------------------------------------------------------------
__global__ __launch_bounds__(256) void k_init(
    const float* __restrict__ w1, const float* __restrict__ w2,
    const float* __restrict__ w3,
    const float* __restrict__ W11, const float* __restrict__ W12,
    const float* __restrict__ W13,
    const float* __restrict__ b11, const float* __restrict__ b12,
    const float* __restrict__ b13,
    ushort* __restrict__ Wtc, ushort* __restrict__ Wp1,
    float* __restrict__ bias_cat,
    float* __restrict__ hg, int* __restrict__ cnt) {
    int idx = blockIdx.x * 256 + threadIdx.x;
    if (idx < N_GRAPHS * 49) hg[idx] = 0.f;
    if (idx < N_NODES) cnt[idx] = 0;
    if (idx < 176)
        bias_cat[idx] = (idx < 54) ? b11[idx] : (idx < 108) ? b12[idx - 54]
                      : (idx < 162) ? b13[idx - 108] : 0.f;
    if (idx < 3 * 12 * 96 * 32) {
        int kl = idx & 31;
        int o  = (idx >> 5) % 96;
        int s  = (idx >> 5) / 96 % 12;
        int k  = idx / (32 * 96 * 12);
        int kk = s * 32 + kl;
        int t = kk >> 7, i = kk & 127;
        const float* w = (k == 0) ? w1 : (k == 1) ? w2 : w3;
        Wtc[idx] = f2bf(w[(o * 128 + i) * 3 + t]);
    }
    if (idx < 3 * 3 * 64 * 32) {
        int kl = idx & 31;
        int o  = (idx >> 5) % 64;
        int s2 = (idx >> 5) / 64 % 3;
        int k  = idx / (32 * 64 * 3);
        int kk2 = s2 * 32 + kl;
        const float* W = (k == 0) ? W11 : (k == 1) ? W12 : W13;
        Wp1[idx] = (o < 54) ? f2bf(W[kk2 * 54 + o]) : (ushort)0;
    }
}

// ---------------------------------------------------------------------------
// k_convscat: FUSED conv + bucket-scatter (r12 structure, LDS shrunk to
// 31.3 KB -> 5 blocks/CU so the 1600 scatter blocks get +25% occupancy).
// 2400 blocks in groups of 8 (preserves blockIdx%8 <-> XCD round-robin):
//   gid = bid>>3, sub = bid&7
//   gid%3==2 -> conv role,   tile = (gid/3)*8 + sub        (800 tiles)
//   else     -> scatter role, chunk c = (gid/3)*2+(gid%3), range r = sub
// Scatter: edge for dst d -> s_pack[d*64 + atomicAdd(cnt[d])]; range r's
// cnt/bucket lines touched only by blocks with bid%8==r (one XCD owner).
// Conv: weight CHUNKS of 2 K-steps ([2][96][32] = 12.3 KB) LDS-staged with
// register prefetch (18 phases); fused relu-combine + [96->54] epilogue.
// ---------------------------------------------------------------------------
#define RNG 6400
#define ECHUNK 4096
#define DEG_MAX 64
#define BN 64
#define XS_LD 136
#define HS_LD 104

__global__ __launch_bounds__(256, 5) void k_convscat(
    const float* __restrict__ x,
    const ushort* __restrict__ Wtc, const ushort* __restrict__ Wp1g,
    const float* __restrict__ b1, const float* __restrict__ b2,
    const float* __restrict__ b3, ushort* __restrict__ hw_cat,
    const int* __restrict__ src, const int* __restrict__ dst,
    const float* __restrict__ ew,
    int* __restrict__ cnt, uint* __restrict__ s_pack) {
    __shared__ ushort xs[70 * XS_LD];     // 19040 B
    __shared__ ushort wl[6144];           // 12288 B: chunk [2][96][32]

    const int tid = threadIdx.x;
    const int gid = blockIdx.x >> 3;
    const int sub = blockIdx.x & 7;

    if (gid % 3 != 2) {
        // ---------------- scatter role ----------------
        int c = (gid / 3) * 2 + (gid % 3);      // chunk 0..199
        int lo = sub * RNG, hi = lo + RNG;
        int base = c * ECHUNK + tid;
#pragma unroll
        for (int i = 0; i < ECHUNK / 256; ++i) {
            int e = base + i * 256;
            int d = dst[e];
            int sv = src[e];
            float wv = ew[e];
            if (d >= lo && d < hi) {
                int pos = atomicAdd(&cnt[d], 1);
                if (pos < DEG_MAX)
                    s_pack[(d << 6) + pos] = ((uint)f2bf(wv) << 16) | (uint)sv;
            }
        }
        return;
    }

    // ---------------- conv role ----------------
    const int tile = (gid / 3) * 8 + sub;       // 0..799
    const int n0   = tile * BN;
    ushort* wp   = wl;                          // epilogue alias (6144 ushorts)
    ushort* hswb = xs;

    for (int idx = tid; idx < 70 * 32; idx += 256) {
        int row = idx >> 5, c4 = (idx & 31) << 2;
        int node = n0 - 3 + row;
        float4 v = make_float4(0.f, 0.f, 0.f, 0.f);
        if (node >= 0 && node < N_NODES)
            v = *reinterpret_cast<const float4*>(x + (size_t)node * 128 + c4);
        ushort* p = &xs[row * XS_LD + c4];
        p[0] = f2bf(v.x); p[1] = f2bf(v.y); p[2] = f2bf(v.z); p[3] = f2bf(v.w);
    }

    const int lane = tid & 63;
    const int wave = tid >> 6;
    const int r16  = lane & 15;
    const int b8   = (lane >> 4) * 8;

    f32x4 acc[3][6];
#pragma unroll
    for (int k = 0; k < 3; ++k)
#pragma unroll
        for (int ot = 0; ot < 6; ++ot) acc[k][ot] = (f32x4)0.f;

    short8 wreg[3];   // 2-K-step chunk: 6144 ushorts / 256 thr = 3 x 16B
#pragma unroll
    for (int i = 0; i < 3; ++i)
        wreg[i] = *reinterpret_cast<const short8*>(Wtc + (i * 256 + tid) * 8);

#pragma unroll
    for (int ch = 0; ch < 18; ++ch) {
        const int k  = ch / 6;          // conv index (static after unroll)
        const int cp = ch % 6;
        __syncthreads();                // prior wl readers (or xs writers) done
#pragma unroll
        for (int i = 0; i < 3; ++i)
            *reinterpret_cast<short8*>(wl + (i * 256 + tid) * 8) = wreg[i];
        __syncthreads();
        if (ch < 17) {                  // prefetch next chunk under MFMAs
            const ushort* nw = Wtc + (size_t)(ch + 1) * 6144;
#pragma unroll
            for (int i = 0; i < 3; ++i)
                wreg[i] = *reinterpret_cast<const short8*>(nw + (i * 256 + tid) * 8);
        }
        const int dk = k + 1;
#pragma unroll
        for (int sp = 0; sp < 2; ++sp) {
            const int s     = cp * 2 + sp;
            const int cbase = (s * 32) & 127;
            const int t     = (s * 32) >> 7;
            const int roff  = (t - 1) * dk + 3;
            short8 a = *reinterpret_cast<const short8*>(
                &xs[(wave * 16 + r16 + roff) * XS_LD + cbase + b8]);
#pragma unroll
            for (int ot = 0; ot < 6; ++ot) {
                short8 b = *reinterpret_cast<const short8*>(
                    &wl[(sp * 96 + ot * 16 + r16) * 32 + b8]);
                acc[k][ot] = __builtin_amdgcn_mfma_f32_16x16x32_bf16(a, b, acc[k][ot], 0, 0, 0);
            }
        }
    }

    // bias + branch combine (in place)
#pragma unroll
    for (int ot = 0; ot < 6; ++ot) {
        int o = ot * 16 + r16;
        float bb1 = b1[o], bb2 = b2[o], bb3 = b3[o];
#pragma unroll
        for (int r = 0; r < 4; ++r) {
            float C1 = acc[0][ot][r] + bb1;
            float C2 = acc[1][ot][r] + bb2;
            float C3 = acc[2][ot][r] + bb3;
            acc[0][ot][r] = fmaxf(C1, 0.f) + C2;
            acc[1][ot][r] = fmaxf(C2, 0.f) + C3;
            acc[2][ot][r] = fmaxf(C3, 0.f) + C1;
        }
    }

    // epilogue: hw_cat[:, 54k:54k+54] = h0k @ W1k  (MFMA, K=96)
    ushort* hs = hswb + wave * (16 * HS_LD);
#pragma unroll
    for (int k = 0; k < 3; ++k) {
        __syncthreads();   // prior wl/wp + hs readers done
        // stage this k's epilogue weights [3][64][32] = 6144 ushorts
#pragma unroll
        for (int i = 0; i < 3; ++i)
            *reinterpret_cast<short8*>(wp + (i * 256 + tid) * 8) =
                *reinterpret_cast<const short8*>(Wp1g + k * 6144 + (i * 256 + tid) * 8);
        // write this k's h0 values into hs
#pragma unroll
        for (int ot = 0; ot < 6; ++ot)
#pragma unroll
            for (int r = 0; r < 4; ++r)
                hs[((lane >> 4) * 4 + r) * HS_LD + ot * 16 + r16] = f2bf(acc[k][ot][r]);
        __syncthreads();
        f32x4 acc2[4];
#pragma unroll
        for (int ot2 = 0; ot2 < 4; ++ot2) acc2[ot2] = (f32x4)0.f;
#pragma unroll
        for (int s2 = 0; s2 < 3; ++s2) {
            short8 a = *reinterpret_cast<const short8*>(&hs[r16 * HS_LD + s2 * 32 + b8]);
#pragma unroll
            for (int ot2 = 0; ot2 < 4; ++ot2) {
                short8 b = *reinterpret_cast<const short8*>(
                    &wp[(s2 * 64 + ot2 * 16 + r16) * 32 + b8]);
                acc2[ot2] = __builtin_amdgcn_mfma_f32_16x16x32_bf16(a, b, acc2[ot2], 0, 0, 0);
            }
        }
#pragma unroll
        for (int ot2 = 0; ot2 < 4; ++ot2) {
            int co = ot2 * 16 + r16;
            if (co < 54) {
#pragma unroll
                for (int r = 0; r < 4; ++r) {
                    int node = n0 + wave * 16 + (lane >> 4) * 4 + r;
                    hw_cat[(size_t)node * 176 + k * 54 + co] = f2bf(acc2[ot2][r]);
                }
            }
        }
    }
    // zero pad cols 162..175
    for (int idx = tid; idx < 64 * 14; idx += 256) {
        int r = idx / 14, c = 162 + (idx - r * 14);
        hw_cat[(size_t)(n0 + r) * 176 + c] = 0;
    }
}

// ---------------------------------------------------------------------------
// k_agg1: bucket aggregate of hw_cat (bf16 [N][176]) -> relu(agg+bias) per
// branch, branch-combine, fused W2 GEMV -> hw2 bf16 [N][28].
// One wave per node; 44 lanes x ushort4 = full 352B row per instruction;
// 16-DEEP gather pipeline: whole bucket meta loaded as 4 x uint4, up to 16
// row-gathers in flight; uniform-branch tail (no wasted gathers).
// ---------------------------------------------------------------------------
__global__ __launch_bounds__(256) void k_agg1(
    const ushort* __restrict__ hw, const int* __restrict__ cnt,
    const uint* __restrict__ pk, const float* __restrict__ bias_cat,
    const float* __restrict__ W2, ushort* __restrict__ hw2) {
    __shared__ float stage[4][176];
    __shared__ float w2s[54 * 25];
    int tid = threadIdx.x;
    for (int i = tid; i < 54 * 25; i += 256) w2s[i] = W2[i];
    int lane = tid & 63, wave = tid >> 6;
    int n = blockIdx.x * 4 + wave;
    const bool act = lane < 44;
    const int col = lane * 4;
    int deg = __builtin_amdgcn_readfirstlane(cnt[n]);
    deg = deg > DEG_MAX ? DEG_MAX : deg;
    const uint4* pk4 = reinterpret_cast<const uint4*>(pk + ((size_t)n << 6));
    float a0 = 0.f, a1 = 0.f, a2 = 0.f, a3 = 0.f;

    auto proc = [&](uint mm) {
        float w = bf2f((ushort)(mm >> 16));
        ushort4 v = *reinterpret_cast<const ushort4*>(
            hw + (size_t)(mm & 0xFFFFu) * 176 + col);
        a0 += w * bf2f(v.x); a1 += w * bf2f(v.y);
        a2 += w * bf2f(v.z); a3 += w * bf2f(v.w);
    };

    int e = 0;
    for (; e + 16 <= deg; e += 16) {
        uint4 M[4];
#pragma unroll
        for (int g = 0; g < 4; ++g) M[g] = pk4[(e >> 2) + g];
        if (act) {
#pragma unroll
            for (int g = 0; g < 4; ++g) {
                proc(M[g].x); proc(M[g].y); proc(M[g].z); proc(M[g].w);
            }
        }
    }
    if (e < deg) {
        uint4 M[4];
#pragma unroll
        for (int g = 0; g < 4; ++g) M[g] = pk4[(e >> 2) + g];  // 64 slots alloc'd
        uint mm[16] = {M[0].x, M[0].y, M[0].z, M[0].w,
                       M[1].x, M[1].y, M[1].z, M[1].w,
                       M[2].x, M[2].y, M[2].z, M[2].w,
                       M[3].x, M[3].y, M[3].z, M[3].w};
        int rem = deg - e;    // 1..15, wave-uniform
#pragma unroll
        for (int u = 0; u < 16; ++u)
            if (u < rem && act) proc(mm[u]);
    }

    if (act) {
        stage[wave][col + 0] = fmaxf(a0 + bias_cat[col + 0], 0.f);
        stage[wave][col + 1] = fmaxf(a1 + bias_cat[col + 1], 0.f);
        stage[wave][col + 2] = fmaxf(a2 + bias_cat[col + 2], 0.f);
        stage[wave][col + 3] = fmaxf(a3 + bias_cat[col + 3], 0.f);
    }
    __syncthreads();          // stage + w2s ready
    if (lane < 54)
        stage[wave][lane] = stage[wave][lane] + stage[wave][lane + 54] +
                            stage[wave][lane + 108];
    if (lane < 25) {
        float acc = 0.f;
#pragma unroll
        for (int i = 0; i < 54; ++i) acc += stage[wave][i] * w2s[i * 25 + lane];
        hw2[(size_t)n * 28 + lane] = f2bf(acc);
    }
}

// ---------------------------------------------------------------------------
// k_agg2: bucket aggregate hw2 (bf16 [N][28], L2-resident) -> relu(agg+b2);
// run-length seg-sum into hg[:,0:25]; fused hw34 = ac_h2 @ [W3|W4].
// ---------------------------------------------------------------------------
__global__ __launch_bounds__(256) void k_agg2(
    const ushort* __restrict__ hw2, const int* __restrict__ cnt,
    const uint* __restrict__ pk,
    const float* __restrict__ b2, const float* __restrict__ W3,
    const float* __restrict__ W4, const int* __restrict__ gids,
    ushort* __restrict__ hw34, float* __restrict__ hg) {
    __shared__ float w34s[25 * 24];
    __shared__ float vst[8][26];
    __shared__ int sgid[8];
    int tid = threadIdx.x;
    for (int i = tid; i < 25 * 24; i += 256) {
        int ii = i / 24, j = i - ii * 24;
        w34s[i] = (j < 13) ? W3[ii * 13 + j] : W4[ii * 11 + (j - 13)];
    }
    int lane = tid & 63, wave = tid >> 6;
    int half = lane >> 5, jj = lane & 31;
    int n0b = blockIdx.x * 8;
    int nl = wave * 2 + half;
    int n = n0b + nl;
    int e0 = n << 6;
    int dcg = cnt[n];
    int e1 = e0 + (dcg > DEG_MAX ? DEG_MAX : dcg);
    float acc = 0.f;
    int e = e0;
    for (; e + 7 < e1; e += 8) {
        uint m[8];
#pragma unroll
        for (int u = 0; u < 8; ++u) m[u] = pk[e + u];
        if (jj < 25) {
#pragma unroll
            for (int u = 0; u < 8; ++u)
                acc += bf2f((ushort)(m[u] >> 16)) *
                       bf2f(hw2[(size_t)(m[u] & 0xFFFFu) * 28 + jj]);
        }
    }
    if (e + 3 < e1) {
        uint m[4];
#pragma unroll
        for (int u = 0; u < 4; ++u) m[u] = pk[e + u];
        if (jj < 25) {
#pragma unroll
            for (int u = 0; u < 4; ++u)
                acc += bf2f((ushort)(m[u] >> 16)) *
                       bf2f(hw2[(size_t)(m[u] & 0xFFFFu) * 28 + jj]);
        }
        e += 4;
    }
    for (; e < e1; ++e) {
        uint m = pk[e];
        if (jj < 25) acc += bf2f((ushort)(m >> 16)) *
                            bf2f(hw2[(size_t)(m & 0xFFFFu) * 28 + jj]);
    }
    if (jj < 25) vst[nl][jj] = fmaxf(acc + b2[jj], 0.f);
    if (jj == 0) sgid[nl] = gids[n];
    __syncthreads();
    if (tid < 25) {
        float run = vst[0][tid];
        int g = sgid[0];
        for (int nn = 1; nn < 8; ++nn) {
            if (sgid[nn] == g) run += vst[nn][tid];
            else { atomicAdd(&hg[g * 49 + tid], run); run = vst[nn][tid]; g = sgid[nn]; }
        }
        atomicAdd(&hg[g * 49 + tid], run);
    }
    if (tid < 192) {
        int node = tid / 24, j = tid - node * 24;
        float a = 0.f;
#pragma unroll
        for (int i = 0; i < 25; ++i) a += vst[node][i] * w34s[i * 24 + j];
        hw34[(size_t)(n0b + node) * 24 + j] = f2bf(a);
    }
}

// ---------------------------------------------------------------------------
// k_agg34: bucket aggregate hw34 (bf16 [N][24], L2-resident) -> relu+bias,
// run-length seg-sum into hg[:,25:49].
// ---------------------------------------------------------------------------
__global__ __launch_bounds__(256) void k_agg34(
    const ushort* __restrict__ hw34, const int* __restrict__ cnt,
    const uint* __restrict__ pk,
    const float* __restrict__ b3, const float* __restrict__ b4,
    const int* __restrict__ gids, float* __restrict__ hg) {
    __shared__ float vst[8][25];
    __shared__ int sgid[8];
    int tid = threadIdx.x;
    int lane = tid & 63, wave = tid >> 6;
    int half = lane >> 5, jj = lane & 31;
    int nl = wave * 2 + half;
    int n = blockIdx.x * 8 + nl;
    int e0 = n << 6;
    int dcg = cnt[n];
    int e1 = e0 + (dcg > DEG_MAX ? DEG_MAX : dcg);
    float acc = 0.f;
    int e = e0;
    for (; e + 7 < e1; e += 8) {
        uint m[8];
#pragma unroll
        for (int u = 0; u < 8; ++u) m[u] = pk[e + u];
        if (jj < 24) {
#pragma unroll
            for (int u = 0; u < 8; ++u)
                acc += bf2f((ushort)(m[u] >> 16)) *
                       bf2f(hw34[(size_t)(m[u] & 0xFFFFu) * 24 + jj]);
        }
    }
    if (e + 3 < e1) {
        uint m[4];
#pragma unroll
        for (int u = 0; u < 4; ++u) m[u] = pk[e + u];
        if (jj < 24) {
#pragma unroll
            for (int u = 0; u < 4; ++u)
                acc += bf2f((ushort)(m[u] >> 16)) *
                       bf2f(hw34[(size_t)(m[u] & 0xFFFFu) * 24 + jj]);
        }
        e += 4;
    }
    for (; e < e1; ++e) {
        uint m = pk[e];
        if (jj < 24) acc += bf2f((ushort)(m >> 16)) *
                            bf2f(hw34[(size_t)(m & 0xFFFFu) * 24 + jj]);
    }
    if (jj < 24) {
        float v = (jj < 13) ? fmaxf(acc + b3[jj], 0.f)
                            : fmaxf(acc + b4[jj - 13], 0.f);
        vst[nl][jj] = v;
    }
    if (jj == 0) sgid[nl] = gids[n];
    __syncthreads();
    if (tid < 24) {
        float run = vst[0][tid];
        int g = sgid[0];
        for (int nn = 1; nn < 8; ++nn) {
            if (sgid[nn] == g) run += vst[nn][tid];
            else { atomicAdd(&hg[g * 49 + 25 + tid], run); run = vst[nn][tid]; g = sgid[nn]; }
        }
        atomicAdd(&hg[g * 49 + 25 + tid], run);
    }
}

// ---------------------------------------------------------------------------
// k_final: out = (hg @ Wc1 + bc1) @ Wc2 + bc2     [256,49]->[256,5]
// ---------------------------------------------------------------------------
__global__ __launch_bounds__(256) void k_final(
    const float* __restrict__ hg, const float* __restrict__ Wc1,
    const float* __restrict__ bc1, const float* __restrict__ Wc2,
    const float* __restrict__ bc2, float* __restrict__ out) {
    int g = blockIdx.x * blockDim.x + threadIdx.x;
    if (g < N_GRAPHS) {
        float t[27];
#pragma unroll
        for (int j = 0; j < 27; ++j) t[j] = bc1[j];
        for (int i = 0; i < 49; ++i) {
            float hv = hg[g * 49 + i];
#pragma unroll
            for (int j = 0; j < 27; ++j) t[j] += hv * Wc1[i * 27 + j];
        }
#pragma unroll
        for (int j2 = 0; j2 < 5; ++j2) {
            float o = bc2[j2];
#pragma unroll
            for (int i = 0; i < 27; ++i) o += t[i] * Wc2[i * 5 + j2];
            out[g * 5 + j2] = o;
        }
    }
}

// ---------------------------------------------------------------------------
extern "C" void kernel_launch(void* const* d_in, const int* in_sizes, int n_in,
                              void* d_out, int out_size, void* d_ws, size_t ws_size,
                              hipStream_t stream) {
    const float* x    = (const float*)d_in[0];
    const int*   src  = (const int*)d_in[1];
    const int*   dst  = (const int*)d_in[2];
    const int*   gids = (const int*)d_in[3];
    const float* ew   = (const float*)d_in[4];
    const float* w1 = (const float*)d_in[5],  *b1 = (const float*)d_in[6];
    const float* w2 = (const float*)d_in[7],  *b2 = (const float*)d_in[8];
    const float* w3 = (const float*)d_in[9],  *b3 = (const float*)d_in[10];
    const float* W11 = (const float*)d_in[11], *b11 = (const float*)d_in[12];
    const float* W12 = (const float*)d_in[13], *b12 = (const float*)d_in[14];
    const float* W13 = (const float*)d_in[15], *b13 = (const float*)d_in[16];
    const float* W2  = (const float*)d_in[17], *b2g = (const float*)d_in[18];
    const float* W3  = (const float*)d_in[19], *b3g = (const float*)d_in[20];
    const float* W4  = (const float*)d_in[21], *b4g = (const float*)d_in[22];
    const float* Wc1 = (const float*)d_in[23], *bc1 = (const float*)d_in[24];
    const float* Wc2 = (const float*)d_in[25], *bc2 = (const float*)d_in[26];
    float* out = (float*)d_out;

    char* ws = (char*)d_ws;
    size_t off = 0;
    auto alloc = [&](size_t bytes) {
        size_t o = off;
        off = (off + bytes + 255) & ~(size_t)255;
        return (void*)(ws + o);
    };
    int*    cnt      = (int*)alloc(N_NODES * 4);
    uint*   s_pack   = (uint*)alloc((size_t)N_NODES * DEG_MAX * 4);   // 13.1 MB
    ushort* hw_cat   = (ushort*)alloc((size_t)N_NODES * 176 * 2);
    ushort* hw2      = (ushort*)alloc((size_t)N_NODES * 28 * 2);
    ushort* hw34     = (ushort*)alloc((size_t)N_NODES * 24 * 2);
    float*  hg       = (float*)alloc(N_GRAPHS * 49 * 4);
    ushort* Wtc      = (ushort*)alloc(3 * 12 * 96 * 32 * 2);
    ushort* Wp1      = (ushort*)alloc(3 * 3 * 64 * 32 * 2);
    float*  bias_cat = (float*)alloc(176 * 4);

    k_init<<<(3 * 12 * 96 * 32 + 255) / 256, 256, 0, stream>>>(
        w1, w2, w3, W11, W12, W13, b11, b12, b13, Wtc, Wp1, bias_cat, hg, cnt);
    // 300 groups x 8 blocks: 200 scatter groups (1600 blocks) + 100 conv
    // groups (800 blocks), interleaved 2:1 for co-scheduling.
    k_convscat<<<2400, 256, 0, stream>>>(x, Wtc, Wp1, b1, b2, b3, hw_cat,
                                         src, dst, ew, cnt, s_pack);
    k_agg1<<<N_NODES / 4, 256, 0, stream>>>(hw_cat, cnt, s_pack,
                                            bias_cat, W2, hw2);
    k_agg2<<<N_NODES / 8, 256, 0, stream>>>(hw2, cnt, s_pack, b2g,
                                            W3, W4, gids, hw34, hg);
    k_agg34<<<N_NODES / 8, 256, 0, stream>>>(hw34, cnt, s_pack, b3g, b4g,
                                             gids, hg);
    k_final<<<1, 256, 0, stream>>>(hg, Wc1, bc1, Wc2, bc2, out);
}

// Round 15
// 194.459 us; speedup vs baseline: 1.1086x; 1.1086x over previous
//
#include <hip/hip_runtime.h>
#include <hip/hip_bf16.h>

#define N_NODES 51200
#define N_EDGES 819200
#define N_GRAPHS 256

typedef __attribute__((ext_vector_type(8))) short short8;
typedef __attribute__((ext_vector_type(4))) float f32x4;

__device__ __forceinline__ ushort f2bf(float f) {
    uint u = __builtin_bit_cast(uint, f);
    u += 0x7FFFu + ((u >> 16) & 1u);     // round-to-nearest-even
    return (ushort)(u >> 16);
}
__device__ __forceinline__ float bf2f(ushort h) {
    uint u = ((uint)h) << 16;
    return __builtin_bit_cast(float, u);
}

// ---------------------------------------------------------------------------
// k_init: zero hg + cnt, pack conv weights, build bias_cat[176]
// ---------------------------------------------------------------------------
__global__ __launch_bounds__(256) void k_init(
    const float* __restrict__ w1, const float* __restrict__ w2,
    const float* __restrict__ w3,
    const float* __restrict__ W11, const float* __restrict__ W12,
    const float* __restrict__ W13,
    const float* __restrict__ b11, const float* __restrict__ b12,
    const float* __restrict__ b13,
    ushort* __restrict__ Wtc, ushort* __restrict__ Wp1,
    float* __restrict__ bias_cat,
    float* __restrict__ hg, int* __restrict__ cnt) {
    int idx = blockIdx.x * 256 + threadIdx.x;
    if (idx < N_GRAPHS * 49) hg[idx] = 0.f;
    if (idx < N_NODES) cnt[idx] = 0;
    if (idx < 176)
        bias_cat[idx] = (idx < 54) ? b11[idx] : (idx < 108) ? b12[idx - 54]
                      : (idx < 162) ? b13[idx - 108] : 0.f;
    if (idx < 3 * 12 * 96 * 32) {
        int kl = idx & 31;
        int o  = (idx >> 5) % 96;
        int s  = (idx >> 5) / 96 % 12;
        int k  = idx / (32 * 96 * 12);
        int kk = s * 32 + kl;
        int t = kk >> 7, i = kk & 127;
        const float* w = (k == 0) ? w1 : (k == 1) ? w2 : w3;
        Wtc[idx] = f2bf(w[(o * 128 + i) * 3 + t]);
    }
    if (idx < 3 * 3 * 64 * 32) {
        int kl = idx & 31;
        int o  = (idx >> 5) % 64;
        int s2 = (idx >> 5) / 64 % 3;
        int k  = idx / (32 * 64 * 3);
        int kk2 = s2 * 32 + kl;
        const float* W = (k == 0) ? W11 : (k == 1) ? W12 : W13;
        Wp1[idx] = (o < 54) ? f2bf(W[kk2 * 54 + o]) : (ushort)0;
    }
}

// ---------------------------------------------------------------------------
// k_convscat: FUSED conv + bucket-scatter (r12 configuration — measured best).
// 2400 blocks in groups of 8 (preserves blockIdx%8 <-> XCD round-robin):
//   gid = bid>>3, sub = bid&7
//   gid%3==2 -> conv role,   tile = (gid/3)*8 + sub        (800 tiles)
//   else     -> scatter role, chunk c = (gid/3)*2+(gid%3), range r = sub
// Scatter: edge for dst d -> s_pack[d*64 + atomicAdd(cnt[d])]; range r's
// cnt/bucket lines touched only by blocks with bid%8==r (one XCD owner).
// Degree ~ Binom(819200,1/51200): mean 16, max ~40 << 64 (guard anyway).
// Conv: weights LDS-staged in quarters w/ register prefetch (37.5 KB LDS,
// 4 blocks/CU), fused relu-combine + [96->54] epilogue -> hw_cat [N][176].
// ---------------------------------------------------------------------------
#define RNG 6400
#define ECHUNK 4096
#define DEG_MAX 64
#define BN 64
#define XS_LD 136
#define HS_LD 104

__global__ __launch_bounds__(256, 4) void k_convscat(
    const float* __restrict__ x,
    const ushort* __restrict__ Wtc, const ushort* __restrict__ Wp1g,
    const float* __restrict__ b1, const float* __restrict__ b2,
    const float* __restrict__ b3, ushort* __restrict__ hw_cat,
    const int* __restrict__ src, const int* __restrict__ dst,
    const float* __restrict__ ew,
    int* __restrict__ cnt, uint* __restrict__ s_pack) {
    __shared__ ushort xs[70 * XS_LD];     // 19040 B
    __shared__ ushort wl[9216];           // 18432 B

    const int tid = threadIdx.x;
    const int gid = blockIdx.x >> 3;
    const int sub = blockIdx.x & 7;

    if (gid % 3 != 2) {
        // ---------------- scatter role ----------------
        int c = (gid / 3) * 2 + (gid % 3);      // chunk 0..199
        int lo = sub * RNG, hi = lo + RNG;
        int base = c * ECHUNK + tid;
#pragma unroll
        for (int i = 0; i < ECHUNK / 256; ++i) {
            int e = base + i * 256;
            int d = dst[e];
            int sv = src[e];
            float wv = ew[e];
            if (d >= lo && d < hi) {
                int pos = atomicAdd(&cnt[d], 1);
                if (pos < DEG_MAX)
                    s_pack[(d << 6) + pos] = ((uint)f2bf(wv) << 16) | (uint)sv;
            }
        }
        return;
    }

    // ---------------- conv role ----------------
    const int tile = (gid / 3) * 8 + sub;       // 0..799
    const int n0   = tile * BN;
    ushort* wp   = wl;
    ushort* hswb = xs;

    for (int idx = tid; idx < 70 * 32; idx += 256) {
        int row = idx >> 5, c4 = (idx & 31) << 2;
        int node = n0 - 3 + row;
        float4 v = make_float4(0.f, 0.f, 0.f, 0.f);
        if (node >= 0 && node < N_NODES)
            v = *reinterpret_cast<const float4*>(x + (size_t)node * 128 + c4);
        ushort* p = &xs[row * XS_LD + c4];
        p[0] = f2bf(v.x); p[1] = f2bf(v.y); p[2] = f2bf(v.z); p[3] = f2bf(v.w);
    }

    const int lane = tid & 63;
    const int wave = tid >> 6;
    const int r16  = lane & 15;
    const int b8   = (lane >> 4) * 8;

    f32x4 acc[3][6];
#pragma unroll
    for (int k = 0; k < 3; ++k)
#pragma unroll
        for (int ot = 0; ot < 6; ++ot) acc[k][ot] = (f32x4)0.f;

    ushort4 wreg[9];
#pragma unroll
    for (int i = 0; i < 9; ++i)
        wreg[i] = *reinterpret_cast<const ushort4*>(Wtc + (i * 256 + tid) * 4);

#pragma unroll
    for (int kq = 0; kq < 12; ++kq) {
        const int k = kq >> 2;
        const int q = kq & 3;
        __syncthreads();
#pragma unroll
        for (int i = 0; i < 9; ++i)
            *reinterpret_cast<ushort4*>(wl + (i * 256 + tid) * 4) = wreg[i];
        __syncthreads();
        if (kq < 11) {
            const ushort* nw = Wtc + (size_t)(kq + 1) * 9216;
#pragma unroll
            for (int i = 0; i < 9; ++i)
                wreg[i] = *reinterpret_cast<const ushort4*>(nw + (i * 256 + tid) * 4);
        }
        const int dk = k + 1;
#pragma unroll
        for (int sp = 0; sp < 3; ++sp) {
            const int s     = q * 3 + sp;
            const int cbase = (s * 32) & 127;
            const int t     = (s * 32) >> 7;
            const int roff  = (t - 1) * dk + 3;
            short8 a = *reinterpret_cast<const short8*>(
                &xs[(wave * 16 + r16 + roff) * XS_LD + cbase + b8]);
#pragma unroll
            for (int ot = 0; ot < 6; ++ot) {
                short8 b = *reinterpret_cast<const short8*>(
                    &wl[(sp * 96 + ot * 16 + r16) * 32 + b8]);
                acc[k][ot] = __builtin_amdgcn_mfma_f32_16x16x32_bf16(a, b, acc[k][ot], 0, 0, 0);
            }
        }
    }

#pragma unroll
    for (int ot = 0; ot < 6; ++ot) {
        int o = ot * 16 + r16;
        float bb1 = b1[o], bb2 = b2[o], bb3 = b3[o];
#pragma unroll
        for (int r = 0; r < 4; ++r) {
            float C1 = acc[0][ot][r] + bb1;
            float C2 = acc[1][ot][r] + bb2;
            float C3 = acc[2][ot][r] + bb3;
            acc[0][ot][r] = fmaxf(C1, 0.f) + C2;
            acc[1][ot][r] = fmaxf(C2, 0.f) + C3;
            acc[2][ot][r] = fmaxf(C3, 0.f) + C1;
        }
    }

    ushort* hs = hswb + wave * (16 * HS_LD);
#pragma unroll
    for (int k = 0; k < 3; ++k) {
        __syncthreads();
#pragma unroll
        for (int i = 0; i < 6; ++i)
            *reinterpret_cast<ushort4*>(wp + (i * 256 + tid) * 4) =
                *reinterpret_cast<const ushort4*>(Wp1g + k * 6144 + (i * 256 + tid) * 4);
#pragma unroll
        for (int ot = 0; ot < 6; ++ot)
#pragma unroll
            for (int r = 0; r < 4; ++r)
                hs[((lane >> 4) * 4 + r) * HS_LD + ot * 16 + r16] = f2bf(acc[k][ot][r]);
        __syncthreads();
        f32x4 acc2[4];
#pragma unroll
        for (int ot2 = 0; ot2 < 4; ++ot2) acc2[ot2] = (f32x4)0.f;
#pragma unroll
        for (int s2 = 0; s2 < 3; ++s2) {
            short8 a = *reinterpret_cast<const short8*>(&hs[r16 * HS_LD + s2 * 32 + b8]);
#pragma unroll
            for (int ot2 = 0; ot2 < 4; ++ot2) {
                short8 b = *reinterpret_cast<const short8*>(
                    &wp[(s2 * 64 + ot2 * 16 + r16) * 32 + b8]);
                acc2[ot2] = __builtin_amdgcn_mfma_f32_16x16x32_bf16(a, b, acc2[ot2], 0, 0, 0);
            }
        }
#pragma unroll
        for (int ot2 = 0; ot2 < 4; ++ot2) {
            int co = ot2 * 16 + r16;
            if (co < 54) {
#pragma unroll
                for (int r = 0; r < 4; ++r) {
                    int node = n0 + wave * 16 + (lane >> 4) * 4 + r;
                    hw_cat[(size_t)node * 176 + k * 54 + co] = f2bf(acc2[ot2][r]);
                }
            }
        }
    }
    // zero pad cols 162..175
    for (int idx = tid; idx < 64 * 14; idx += 256) {
        int r = idx / 14, c = 162 + (idx - r * 14);
        hw_cat[(size_t)(n0 + r) * 176 + c] = 0;
    }
}

// ---------------------------------------------------------------------------
// k_agg1: bucket aggregate of hw_cat (bf16 [N][176]) -> relu(agg+bias) per
// branch, branch-combine, fused W2 GEMV -> hw2 bf16 [N][28].
// One wave per node; 44 lanes x ushort4 = full 352B row per instruction;
// 8-deep row gathers + NEXT-group meta prefetch (software pipeline).
// ---------------------------------------------------------------------------
__global__ __launch_bounds__(256) void k_agg1(
    const ushort* __restrict__ hw, const int* __restrict__ cnt,
    const uint* __restrict__ pk, const float* __restrict__ bias_cat,
    const float* __restrict__ W2, ushort* __restrict__ hw2) {
    __shared__ float stage[4][176];
    __shared__ float w2s[54 * 25];
    int tid = threadIdx.x;
    for (int i = tid; i < 54 * 25; i += 256) w2s[i] = W2[i];
    int lane = tid & 63, wave = tid >> 6;
    int n = blockIdx.x * 4 + wave;
    const bool act = lane < 44;
    const int col = lane * 4;
    int e0 = n << 6;
    int e1 = e0 + __builtin_amdgcn_readfirstlane(cnt[n]);
    float a0 = 0.f, a1 = 0.f, a2 = 0.f, a3 = 0.f;
    int e = e0;
    if (e + 7 < e1) {
        uint m[8];
#pragma unroll
        for (int u = 0; u < 8; ++u) m[u] = pk[e + u];
        for (;;) {
            bool more = (e + 15 < e1);
            uint mn[8];
            if (more) {
#pragma unroll
                for (int u = 0; u < 8; ++u) mn[u] = pk[e + 8 + u];
            }
            if (act) {
#pragma unroll
                for (int u = 0; u < 8; ++u) {
                    float w = bf2f((ushort)(m[u] >> 16));
                    ushort4 v = *reinterpret_cast<const ushort4*>(
                        hw + (size_t)(m[u] & 0xFFFFu) * 176 + col);
                    a0 += w * bf2f(v.x); a1 += w * bf2f(v.y);
                    a2 += w * bf2f(v.z); a3 += w * bf2f(v.w);
                }
            }
            e += 8;
            if (!more) break;
#pragma unroll
            for (int u = 0; u < 8; ++u) m[u] = mn[u];
        }
    }
    if (e + 3 < e1) {
        uint m[4];
#pragma unroll
        for (int u = 0; u < 4; ++u) m[u] = pk[e + u];
        if (act) {
#pragma unroll
            for (int u = 0; u < 4; ++u) {
                float w = bf2f((ushort)(m[u] >> 16));
                ushort4 v = *reinterpret_cast<const ushort4*>(
                    hw + (size_t)(m[u] & 0xFFFFu) * 176 + col);
                a0 += w * bf2f(v.x); a1 += w * bf2f(v.y);
                a2 += w * bf2f(v.z); a3 += w * bf2f(v.w);
            }
        }
        e += 4;
    }
    for (; e < e1; ++e) {
        uint m = pk[e];
        if (act) {
            float w = bf2f((ushort)(m >> 16));
            ushort4 v = *reinterpret_cast<const ushort4*>(
                hw + (size_t)(m & 0xFFFFu) * 176 + col);
            a0 += w * bf2f(v.x); a1 += w * bf2f(v.y);
            a2 += w * bf2f(v.z); a3 += w * bf2f(v.w);
        }
    }
    if (act) {
        stage[wave][col + 0] = fmaxf(a0 + bias_cat[col + 0], 0.f);
        stage[wave][col + 1] = fmaxf(a1 + bias_cat[col + 1], 0.f);
        stage[wave][col + 2] = fmaxf(a2 + bias_cat[col + 2], 0.f);
        stage[wave][col + 3] = fmaxf(a3 + bias_cat[col + 3], 0.f);
    }
    __syncthreads();          // stage + w2s ready
    if (lane < 54)
        stage[wave][lane] = stage[wave][lane] + stage[wave][lane + 54] +
                            stage[wave][lane + 108];
    if (lane < 25) {
        float acc = 0.f;
#pragma unroll
        for (int i = 0; i < 54; ++i) acc += stage[wave][i] * w2s[i * 25 + lane];
        hw2[(size_t)n * 28 + lane] = f2bf(acc);
    }
}

// ---------------------------------------------------------------------------
// k_agg2: bucket aggregate hw2 (bf16 [N][28], L2-resident) -> relu(agg+b2);
// run-length seg-sum into hg[:,0:25]; fused hw34 = ac_h2 @ [W3|W4].
// 8 nodes/block, 2 per wave; 8/4/1 edge unroll.
// ---------------------------------------------------------------------------
__global__ __launch_bounds__(256) void k_agg2(
    const ushort* __restrict__ hw2, const int* __restrict__ cnt,
    const uint* __restrict__ pk,
    const float* __restrict__ b2, const float* __restrict__ W3,
    const float* __restrict__ W4, const int* __restrict__ gids,
    ushort* __restrict__ hw34, float* __restrict__ hg) {
    __shared__ float w34s[25 * 24];
    __shared__ float vst[8][26];
    __shared__ int sgid[8];
    int tid = threadIdx.x;
    for (int i = tid; i < 25 * 24; i += 256) {
        int ii = i / 24, j = i - ii * 24;
        w34s[i] = (j < 13) ? W3[ii * 13 + j] : W4[ii * 11 + (j - 13)];
    }
    int lane = tid & 63, wave = tid >> 6;
    int half = lane >> 5, jj = lane & 31;
    int n0b = blockIdx.x * 8;
    int nl = wave * 2 + half;
    int n = n0b + nl;
    int e0 = n << 6;
    int e1 = e0 + cnt[n];
    float acc = 0.f;
    int e = e0;
    for (; e + 7 < e1; e += 8) {
        uint m[8];
#pragma unroll
        for (int u = 0; u < 8; ++u) m[u] = pk[e + u];
        if (jj < 25) {
#pragma unroll
            for (int u = 0; u < 8; ++u)
                acc += bf2f((ushort)(m[u] >> 16)) *
                       bf2f(hw2[(size_t)(m[u] & 0xFFFFu) * 28 + jj]);
        }
    }
    if (e + 3 < e1) {
        uint m[4];
#pragma unroll
        for (int u = 0; u < 4; ++u) m[u] = pk[e + u];
        if (jj < 25) {
#pragma unroll
            for (int u = 0; u < 4; ++u)
                acc += bf2f((ushort)(m[u] >> 16)) *
                       bf2f(hw2[(size_t)(m[u] & 0xFFFFu) * 28 + jj]);
        }
        e += 4;
    }
    for (; e < e1; ++e) {
        uint m = pk[e];
        if (jj < 25) acc += bf2f((ushort)(m >> 16)) *
                            bf2f(hw2[(size_t)(m & 0xFFFFu) * 28 + jj]);
    }
    if (jj < 25) vst[nl][jj] = fmaxf(acc + b2[jj], 0.f);
    if (jj == 0) sgid[nl] = gids[n];
    __syncthreads();
    if (tid < 25) {
        float run = vst[0][tid];
        int g = sgid[0];
        for (int nn = 1; nn < 8; ++nn) {
            if (sgid[nn] == g) run += vst[nn][tid];
            else { atomicAdd(&hg[g * 49 + tid], run); run = vst[nn][tid]; g = sgid[nn]; }
        }
        atomicAdd(&hg[g * 49 + tid], run);
    }
    if (tid < 192) {
        int node = tid / 24, j = tid - node * 24;
        float a = 0.f;
#pragma unroll
        for (int i = 0; i < 25; ++i) a += vst[node][i] * w34s[i * 24 + j];
        hw34[(size_t)(n0b + node) * 24 + j] = f2bf(a);
    }
}

// ---------------------------------------------------------------------------
// k_agg34: bucket aggregate hw34 (bf16 [N][24], L2-resident) -> relu+bias,
// run-length seg-sum into hg[:,25:49]. 8 nodes/block, 2 per wave; 8/4/1.
// ---------------------------------------------------------------------------
__global__ __launch_bounds__(256) void k_agg34(
    const ushort* __restrict__ hw34, const int* __restrict__ cnt,
    const uint* __restrict__ pk,
    const float* __restrict__ b3, const float* __restrict__ b4,
    const int* __restrict__ gids, float* __restrict__ hg) {
    __shared__ float vst[8][25];
    __shared__ int sgid[8];
    int tid = threadIdx.x;
    int lane = tid & 63, wave = tid >> 6;
    int half = lane >> 5, jj = lane & 31;
    int nl = wave * 2 + half;
    int n = blockIdx.x * 8 + nl;
    int e0 = n << 6;
    int e1 = e0 + cnt[n];
    float acc = 0.f;
    int e = e0;
    for (; e + 7 < e1; e += 8) {
        uint m[8];
#pragma unroll
        for (int u = 0; u < 8; ++u) m[u] = pk[e + u];
        if (jj < 24) {
#pragma unroll
            for (int u = 0; u < 8; ++u)
                acc += bf2f((ushort)(m[u] >> 16)) *
                       bf2f(hw34[(size_t)(m[u] & 0xFFFFu) * 24 + jj]);
        }
    }
    if (e + 3 < e1) {
        uint m[4];
#pragma unroll
        for (int u = 0; u < 4; ++u) m[u] = pk[e + u];
        if (jj < 24) {
#pragma unroll
            for (int u = 0; u < 4; ++u)
                acc += bf2f((ushort)(m[u] >> 16)) *
                       bf2f(hw34[(size_t)(m[u] & 0xFFFFu) * 24 + jj]);
        }
        e += 4;
    }
    for (; e < e1; ++e) {
        uint m = pk[e];
        if (jj < 24) acc += bf2f((ushort)(m >> 16)) *
                            bf2f(hw34[(size_t)(m & 0xFFFFu) * 24 + jj]);
    }
    if (jj < 24) {
        float v = (jj < 13) ? fmaxf(acc + b3[jj], 0.f)
                            : fmaxf(acc + b4[jj - 13], 0.f);
        vst[nl][jj] = v;
    }
    if (jj == 0) sgid[nl] = gids[n];
    __syncthreads();
    if (tid < 24) {
        float run = vst[0][tid];
        int g = sgid[0];
        for (int nn = 1; nn < 8; ++nn) {
            if (sgid[nn] == g) run += vst[nn][tid];
            else { atomicAdd(&hg[g * 49 + 25 + tid], run); run = vst[nn][tid]; g = sgid[nn]; }
        }
        atomicAdd(&hg[g * 49 + 25 + tid], run);
    }
}

// ---------------------------------------------------------------------------
// k_final: out = (hg @ Wc1 + bc1) @ Wc2 + bc2     [256,49]->[256,5]
// ---------------------------------------------------------------------------
__global__ __launch_bounds__(256) void k_final(
    const float* __restrict__ hg, const float* __restrict__ Wc1,
    const float* __restrict__ bc1, const float* __restrict__ Wc2,
    const float* __restrict__ bc2, float* __restrict__ out) {
    int g = blockIdx.x * blockDim.x + threadIdx.x;
    if (g < N_GRAPHS) {
        float t[27];
#pragma unroll
        for (int j = 0; j < 27; ++j) t[j] = bc1[j];
        for (int i = 0; i < 49; ++i) {
            float hv = hg[g * 49 + i];
#pragma unroll
            for (int j = 0; j < 27; ++j) t[j] += hv * Wc1[i * 27 + j];
        }
#pragma unroll
        for (int j2 = 0; j2 < 5; ++j2) {
            float o = bc2[j2];
#pragma unroll
            for (int i = 0; i < 27; ++i) o += t[i] * Wc2[i * 5 + j2];
            out[g * 5 + j2] = o;
        }
    }
}

// ---------------------------------------------------------------------------
extern "C" void kernel_launch(void* const* d_in, const int* in_sizes, int n_in,
                              void* d_out, int out_size, void* d_ws, size_t ws_size,
                              hipStream_t stream) {
    const float* x    = (const float*)d_in[0];
    const int*   src  = (const int*)d_in[1];
    const int*   dst  = (const int*)d_in[2];
    const int*   gids = (const int*)d_in[3];
    const float* ew   = (const float*)d_in[4];
    const float* w1 = (const float*)d_in[5],  *b1 = (const float*)d_in[6];
    const float* w2 = (const float*)d_in[7],  *b2 = (const float*)d_in[8];
    const float* w3 = (const float*)d_in[9],  *b3 = (const float*)d_in[10];
    const float* W11 = (const float*)d_in[11], *b11 = (const float*)d_in[12];
    const float* W12 = (const float*)d_in[13], *b12 = (const float*)d_in[14];
    const float* W13 = (const float*)d_in[15], *b13 = (const float*)d_in[16];
    const float* W2  = (const float*)d_in[17], *b2g = (const float*)d_in[18];
    const float* W3  = (const float*)d_in[19], *b3g = (const float*)d_in[20];
    const float* W4  = (const float*)d_in[21], *b4g = (const float*)d_in[22];
    const float* Wc1 = (const float*)d_in[23], *bc1 = (const float*)d_in[24];
    const float* Wc2 = (const float*)d_in[25], *bc2 = (const float*)d_in[26];
    float* out = (float*)d_out;

    char* ws = (char*)d_ws;
    size_t off = 0;
    auto alloc = [&](size_t bytes) {
        size_t o = off;
        off = (off + bytes + 255) & ~(size_t)255;
        return (void*)(ws + o);
    };
    int*    cnt      = (int*)alloc(N_NODES * 4);
    uint*   s_pack   = (uint*)alloc((size_t)N_NODES * DEG_MAX * 4);   // 13.1 MB
    ushort* hw_cat   = (ushort*)alloc((size_t)N_NODES * 176 * 2);
    ushort* hw2      = (ushort*)alloc((size_t)N_NODES * 28 * 2);
    ushort* hw34     = (ushort*)alloc((size_t)N_NODES * 24 * 2);
    float*  hg       = (float*)alloc(N_GRAPHS * 49 * 4);
    ushort* Wtc      = (ushort*)alloc(3 * 12 * 96 * 32 * 2);
    ushort* Wp1      = (ushort*)alloc(3 * 3 * 64 * 32 * 2);
    float*  bias_cat = (float*)alloc(176 * 4);

    k_init<<<(3 * 12 * 96 * 32 + 255) / 256, 256, 0, stream>>>(
        w1, w2, w3, W11, W12, W13, b11, b12, b13, Wtc, Wp1, bias_cat, hg, cnt);
    // 300 groups x 8 blocks: 200 scatter groups (1600 blocks) + 100 conv
    // groups (800 blocks), interleaved 2:1 for co-scheduling.
    k_convscat<<<2400, 256, 0, stream>>>(x, Wtc, Wp1, b1, b2, b3, hw_cat,
                                         src, dst, ew, cnt, s_pack);
    k_agg1<<<N_NODES / 4, 256, 0, stream>>>(hw_cat, cnt, s_pack,
                                            bias_cat, W2, hw2);
    k_agg2<<<N_NODES / 8, 256, 0, stream>>>(hw2, cnt, s_pack, b2g,
                                            W3, W4, gids, hw34, hg);
    k_agg34<<<N_NODES / 8, 256, 0, stream>>>(hw34, cnt, s_pack, b3g, b4g,
                                             gids, hg);
    k_final<<<1, 256, 0, stream>>>(hg, Wc1, bc1, Wc2, bc2, out);
}